// Round 5
// baseline (192.499 us; speedup 1.0000x reference)
//
#include <hip/hip_runtime.h>
#include <hip/hip_bf16.h>

#define N_SRCN 200000
#define N_DSTN 50000
#define NEDGE 800000
#define KIN 256
#define NF 192        // H*OUT = 3*64
#define SLOPE 0.2f
#define NBLK 512      // persistent blocks for gemm
#define NRB 3125      // row-blocks of 64

typedef __attribute__((ext_vector_type(8))) short bf16x8;
typedef __attribute__((ext_vector_type(4))) float f32x4;

__device__ __forceinline__ unsigned short f2bf(float f) {
    union { float f; unsigned int u; } v; v.f = f;
    unsigned int u = v.u;
    return (unsigned short)((u + 0x7FFFu + ((u >> 16) & 1u)) >> 16);  // RNE
}
__device__ __forceinline__ float bf2f(unsigned short h) {
    union { unsigned int u; float f; } v; v.u = ((unsigned int)h) << 16;
    return v.f;
}
__device__ __forceinline__ unsigned int cvt2(float lo, float hi) {
    __hip_bfloat162 h = __float22bfloat162_rn(float2{lo, hi});
    union { __hip_bfloat162 h; unsigned int u; } c; c.h = h;
    return c.u;
}
__device__ __forceinline__ void gl_lds16(const void* g, void* l) {
    __builtin_amdgcn_global_load_lds(
        (const __attribute__((address_space(1))) unsigned int*)g,
        (__attribute__((address_space(3))) unsigned int*)l, 16, 0, 0);
}

// ---------------- prep: pack W (f32 [192][256]) into bf16 fragment-major -----
// Wp[((ks*12 + nt)*64 + lane)*8 + j] = bf16(W[nt*16 + (lane&15)][ks*32 + (lane>>4)*8 + j])
__global__ void prep_w(const float* __restrict__ W, unsigned short* __restrict__ Wp) {
    int tid = blockIdx.x * blockDim.x + threadIdx.x;
    if (tid >= 12 * 8 * 64) return;
    int lane = tid & 63;
    int g = tid >> 6;
    int nt = g % 12, ks = g / 12;
    int col = nt * 16 + (lane & 15);
    int k = ks * 32 + (lane >> 4) * 8;
    const float* wsrc = &W[col * KIN + k];
    unsigned short* o = &Wp[tid * 8];
    #pragma unroll
    for (int j = 0; j < 8; ++j) o[j] = f2bf(wsrc[j]);
}

// ---------------- row_ptr: lower_bound of each d in sorted dst ----------------
__global__ void rowptr_kernel(const int* __restrict__ dst, int* __restrict__ rp) {
    int d = blockIdx.x * blockDim.x + threadIdx.x;
    if (d > N_DSTN) return;
    int lo = 0, hi = NEDGE;
    while (lo < hi) {
        int mid = (lo + hi) >> 1;
        if (dst[mid] < d) lo = mid + 1; else hi = mid;
    }
    rp[d] = lo;
}

// ---------------- GEMM: feat = x @ W^T (bf16 MFMA) + fused el/er -------------
// Persistent: 512 blocks grid-stride over 3125 row-blocks of 64 rows.
// Wave w owns col-tiles nt = {3w, 3w+1, 3w+2} (48 cols) for ALL 64 rows:
// its 24 B-fragments (96 VGPR) load ONCE per kernel -> B-traffic ~24 MB total
// (was 1.2 GB/launch from L2). A staged per-iter via global_load_lds DMA with
// both-sides quad XOR swizzle (conflict-free ds_read_b128).
__launch_bounds__(256, 2)
__global__ void gemm_feat(const float* __restrict__ x, const unsigned short* __restrict__ Wp,
                          const float* __restrict__ attn_l, const float* __restrict__ attn_r,
                          unsigned short* __restrict__ feat,
                          float* __restrict__ el, float* __restrict__ er) {
    __shared__ float Abuf[64][256];          // 64 KB
    __shared__ float parts[64][4][4][2];     // 8 KB  [row][head(pad4)][nt&3][l/r]
    const int t = threadIdx.x;
    const int wid = t >> 6, lane = t & 63;
    const int al = lane & 15, ah = lane >> 4;

    // ---- B preload (once): wave w -> nt = 3w+j ----
    bf16x8 bv[8][3];
    #pragma unroll
    for (int ks = 0; ks < 8; ++ks)
        #pragma unroll
        for (int j = 0; j < 3; ++j)
            bv[ks][j] = *(const bf16x8*)&Wp[(size_t)(ks * 12 + wid * 3 + j) * 512 + lane * 8];

    float Al[3], Ar[3];
    #pragma unroll
    for (int j = 0; j < 3; ++j) {
        Al[j] = attn_l[(wid * 3 + j) * 16 + al];
        Ar[j] = attn_r[(wid * 3 + j) * 16 + al];
    }

    for (int rb = blockIdx.x; rb < NRB; rb += NBLK) {
        const int r0 = rb * 64;

        // ---- stage: wave w DMAs rows [w*16, w*16+16), 1 row (1KB) per call.
        // LDS quad q holds global quad q^(row&7)  (pre-swizzled source).
        #pragma unroll
        for (int rr = 0; rr < 16; ++rr) {
            const int rl = wid * 16 + rr;
            const float* gp = &x[(size_t)(r0 + rl) * KIN + ((lane ^ (rl & 7)) << 2)];
            gl_lds16(gp, &Abuf[rl][0]);
        }
        asm volatile("s_waitcnt vmcnt(0)" ::: "memory");
        __syncthreads();

        // ---- compute: 4 row-tiles x 8 ks x 3 nt ----
        f32x4 acc[4][3] = {};
        #pragma unroll
        for (int rt = 0; rt < 4; ++rt) {
            const int row = rt * 16 + al;
            const int sw = row & 7;
            #pragma unroll
            for (int ks = 0; ks < 8; ++ks) {
                const int q0 = ks * 8 + ah * 2;
                const float4 v0 = *(const float4*)&Abuf[row][((q0 ^ sw) << 2)];
                const float4 v1 = *(const float4*)&Abuf[row][(((q0 + 1) ^ sw) << 2)];
                union { bf16x8 v; unsigned int u[4]; } av;
                av.u[0] = cvt2(v0.x, v0.y);
                av.u[1] = cvt2(v0.z, v0.w);
                av.u[2] = cvt2(v1.x, v1.y);
                av.u[3] = cvt2(v1.z, v1.w);
                #pragma unroll
                for (int j = 0; j < 3; ++j)
                    acc[rt][j] = __builtin_amdgcn_mfma_f32_16x16x32_bf16(av.v, bv[ks][j], acc[rt][j], 0, 0, 0);
            }
        }

        // ---- epilogue 1: feat store (C/D: col=nt*16+al, row=ah*4+e [m89]) ----
        #pragma unroll
        for (int rt = 0; rt < 4; ++rt)
            #pragma unroll
            for (int j = 0; j < 3; ++j) {
                const int col = (wid * 3 + j) * 16 + al;
                #pragma unroll
                for (int e = 0; e < 4; ++e) {
                    const int row = r0 + rt * 16 + ah * 4 + e;
                    feat[(size_t)row * NF + col] = f2bf(acc[rt][j][e]);
                }
            }

        // ---- epilogue 2: el/er partials (16-lane reduce per nt) ----
        #pragma unroll
        for (int rt = 0; rt < 4; ++rt)
            #pragma unroll
            for (int e = 0; e < 4; ++e)
                #pragma unroll
                for (int j = 0; j < 3; ++j) {
                    float sl = acc[rt][j][e] * Al[j];
                    float sr = acc[rt][j][e] * Ar[j];
                    #pragma unroll
                    for (int m = 1; m <= 8; m <<= 1) {
                        sl += __shfl_xor(sl, m);
                        sr += __shfl_xor(sr, m);
                    }
                    if (al == 0) {
                        const int rloc = rt * 16 + ah * 4 + e;
                        const int nt = wid * 3 + j;
                        parts[rloc][nt >> 2][nt & 3][0] = sl;
                        parts[rloc][nt >> 2][nt & 3][1] = sr;
                    }
                }
        __syncthreads();

        // ---- reduce parts -> el/er (256 thr: row = t>>2, h = t&3, skip h==3) --
        if ((t & 3) < 3) {
            const int rloc = t >> 2, h = t & 3;
            float sl = parts[rloc][h][0][0] + parts[rloc][h][1][0]
                     + parts[rloc][h][2][0] + parts[rloc][h][3][0];
            const int row = r0 + rloc;
            el[row * 3 + h] = sl;
            if (row < N_DSTN) {
                float sr = parts[rloc][h][0][1] + parts[rloc][h][1][1]
                         + parts[rloc][h][2][1] + parts[rloc][h][3][1];
                er[row * 3 + h] = sr;
            }
        }
        // next iter's DMA writes Abuf only after all waves pass the next
        // __syncthreads; parts reads precede it in program order -> safe.
    }
}

// ---------------- gather: edge softmax (no max shift) + weighted accumulate --
__launch_bounds__(256)
__global__ void gather_kernel(const unsigned short* __restrict__ feat,
                              const float* __restrict__ el, const float* __restrict__ er,
                              const int* __restrict__ src, const int* __restrict__ rp,
                              float* __restrict__ out) {
    const int lane = threadIdx.x & 63;
    const int d = (blockIdx.x * blockDim.x + threadIdx.x) >> 6;
    if (d >= N_DSTN) return;
    const int lo = rp[d], hi = rp[d + 1];
    const float er0 = er[d * 3 + 0], er1 = er[d * 3 + 1], er2 = er[d * 3 + 2];

    float a0 = 0.f, a1 = 0.f, a2 = 0.f, s0 = 0.f, s1 = 0.f, s2 = 0.f;
    for (int base = lo; base < hi; base += 64) {
        const int cnt = min(64, hi - base);
        int sv = 0; float w0 = 0.f, w1 = 0.f, w2 = 0.f;
        if (lane < cnt) {
            sv = src[base + lane];
            float e0 = el[sv * 3 + 0] + er0; e0 = e0 >= 0.f ? e0 : SLOPE * e0; w0 = __expf(e0);
            float e1 = el[sv * 3 + 1] + er1; e1 = e1 >= 0.f ? e1 : SLOPE * e1; w1 = __expf(e1);
            float e2 = el[sv * 3 + 2] + er2; e2 = e2 >= 0.f ? e2 : SLOPE * e2; w2 = __expf(e2);
        }
        int j = 0;
        for (; j + 8 <= cnt; j += 8) {
            unsigned short f0[8], f1[8], f2[8];
            float u0[8], u1[8], u2[8];
            #pragma unroll
            for (int q = 0; q < 8; ++q) {
                const int sj = __shfl(sv, j + q);
                const unsigned short* fp = &feat[(size_t)sj * NF + lane];
                f0[q] = fp[0]; f1[q] = fp[64]; f2[q] = fp[128];
                u0[q] = __shfl(w0, j + q);
                u1[q] = __shfl(w1, j + q);
                u2[q] = __shfl(w2, j + q);
            }
            #pragma unroll
            for (int q = 0; q < 8; ++q) {
                s0 += u0[q]; a0 += u0[q] * bf2f(f0[q]);
                s1 += u1[q]; a1 += u1[q] * bf2f(f1[q]);
                s2 += u2[q]; a2 += u2[q] * bf2f(f2[q]);
            }
        }
        for (; j < cnt; ++j) {
            const int sj = __shfl(sv, j);
            const float u0 = __shfl(w0, j);
            const float u1 = __shfl(w1, j);
            const float u2 = __shfl(w2, j);
            const unsigned short* fp = &feat[(size_t)sj * NF + lane];
            s0 += u0; a0 += u0 * bf2f(fp[0]);
            s1 += u1; a1 += u1 * bf2f(fp[64]);
            s2 += u2; a2 += u2 * bf2f(fp[128]);
        }
    }
    if (hi == lo) { s0 = 1.f; s1 = 1.f; s2 = 1.f; }
    float* op = &out[(size_t)d * NF];
    op[lane]       = a0 / s0;
    op[64 + lane]  = a1 / s1;
    op[128 + lane] = a2 / s2;
}

extern "C" void kernel_launch(void* const* d_in, const int* in_sizes, int n_in,
                              void* d_out, int out_size, void* d_ws, size_t ws_size,
                              hipStream_t stream) {
    const float* x      = (const float*)d_in[0];
    const float* W      = (const float*)d_in[1];
    const float* attn_l = (const float*)d_in[2];
    const float* attn_r = (const float*)d_in[3];
    const int*   src    = (const int*)d_in[4];
    const int*   dst    = (const int*)d_in[5];
    float* out = (float*)d_out;

    char* ws = (char*)d_ws;
    unsigned short* feat = (unsigned short*)ws;             // 76,800,000 B
    float* el = (float*)(ws + 76800000);                    //  2,400,000 B
    float* er = (float*)(ws + 79200000);                    //    600,000 B
    unsigned short* Wp = (unsigned short*)(ws + 79800000);  //     98,304 B
    int*   rp = (int*)(ws + 79898304);                      //    200,004 B

    prep_w<<<24, 256, 0, stream>>>(W, Wp);
    rowptr_kernel<<<(N_DSTN + 1 + 255) / 256, 256, 0, stream>>>(dst, rp);
    gemm_feat<<<NBLK, 256, 0, stream>>>(x, Wp, attn_l, attn_r, feat, el, er);
    gather_kernel<<<12500, 256, 0, stream>>>(feat, el, er, src, rp, out);
}

// Round 6
// 180.148 us; speedup vs baseline: 1.0686x; 1.0686x over previous
//
#include <hip/hip_runtime.h>
#include <hip/hip_bf16.h>

#define N_SRCN 200000
#define N_DSTN 50000
#define NEDGE 800000
#define KIN 256
#define NF 192        // H*OUT = 3*64
#define SLOPE 0.2f

typedef __attribute__((ext_vector_type(8))) short bf16x8;
typedef __attribute__((ext_vector_type(4))) float f32x4;

__device__ __forceinline__ unsigned short f2bf(float f) {
    union { float f; unsigned int u; } v; v.f = f;
    unsigned int u = v.u;
    return (unsigned short)((u + 0x7FFFu + ((u >> 16) & 1u)) >> 16);  // RNE
}
__device__ __forceinline__ float bf2f(unsigned short h) {
    union { unsigned int u; float f; } v; v.u = ((unsigned int)h) << 16;
    return v.f;
}
__device__ __forceinline__ unsigned int cvt2(float lo, float hi) {
    __hip_bfloat162 h = __float22bfloat162_rn(float2{lo, hi});
    union { __hip_bfloat162 h; unsigned int u; } c; c.h = h;
    return c.u;
}

// ---------------- merged prep: blocks 0-23 pack W; blocks 24+ build row_ptr --
// Wp[((ks*12 + nt)*64 + lane)*8 + j] = bf16(W[nt*16 + (lane&15)][ks*32 + (lane>>4)*8 + j])
__global__ void prep_kernel(const float* __restrict__ W, unsigned short* __restrict__ Wp,
                            const int* __restrict__ dst, int* __restrict__ rp) {
    const int bid = blockIdx.x;
    if (bid < 24) {
        int tid = bid * 256 + threadIdx.x;
        if (tid >= 12 * 8 * 64) return;
        int lane = tid & 63;
        int g = tid >> 6;
        int nt = g % 12, ks = g / 12;
        int col = nt * 16 + (lane & 15);
        int k = ks * 32 + (lane >> 4) * 8;
        const float* wsrc = &W[col * KIN + k];
        unsigned short* o = &Wp[tid * 8];
        #pragma unroll
        for (int j = 0; j < 8; ++j) o[j] = f2bf(wsrc[j]);
    } else {
        int d = (bid - 24) * 256 + threadIdx.x;
        if (d > N_DSTN) return;
        int lo = 0, hi = NEDGE;
        while (lo < hi) {
            int mid = (lo + hi) >> 1;
            if (dst[mid] < d) lo = mid + 1; else hi = mid;
        }
        rp[d] = lo;
    }
}

// ---------------- GEMM: feat = x @ W^T (bf16 MFMA) + fused el/er -------------
// 12500 INDEPENDENT single-wave blocks (64 thr), one 16-row tile each.
// No LDS, no barriers; 2-stage explicit A prefetch (scalar regs, all-static);
// B streams from packed Wp via L1/L2. Max TLP: up to 16 waves/CU co-resident.
__launch_bounds__(64, 4)
__global__ void gemm_feat(const float* __restrict__ x, const unsigned short* __restrict__ Wp,
                          const float* __restrict__ attn_l, const float* __restrict__ attn_r,
                          unsigned short* __restrict__ feat,
                          float* __restrict__ el, float* __restrict__ er) {
    const int lane = threadIdx.x;
    const int al = lane & 15, ah = lane >> 4;
    const int r0 = blockIdx.x * 16;

    const float* xrow = &x[(size_t)(r0 + al) * KIN + ah * 8];

    f32x4 acc[12] = {};
    float4 c0 = *(const float4*)&xrow[0];
    float4 c1 = *(const float4*)&xrow[4];

    #pragma unroll
    for (int ks = 0; ks < 8; ++ks) {
        float4 n0, n1;
        if (ks < 7) {
            n0 = *(const float4*)&xrow[(ks + 1) * 32];
            n1 = *(const float4*)&xrow[(ks + 1) * 32 + 4];
        }
        union { bf16x8 v; unsigned int u[4]; } av;
        av.u[0] = cvt2(c0.x, c0.y);
        av.u[1] = cvt2(c0.z, c0.w);
        av.u[2] = cvt2(c1.x, c1.y);
        av.u[3] = cvt2(c1.z, c1.w);
        const unsigned short* wbase = &Wp[(size_t)(ks * 12) * 512 + lane * 8];
        #pragma unroll
        for (int nt = 0; nt < 12; ++nt) {
            bf16x8 bv = *(const bf16x8*)&wbase[nt * 512];
            acc[nt] = __builtin_amdgcn_mfma_f32_16x16x32_bf16(av.v, bv, acc[nt], 0, 0, 0);
        }
        if (ks < 7) { c0 = n0; c1 = n1; }
    }

    // epilogue 1: feat store (C/D layout: col=al+nt*16, row=ah*4+e  [m89])
    #pragma unroll
    for (int nt = 0; nt < 12; ++nt) {
        const int col = nt * 16 + al;
        #pragma unroll
        for (int e = 0; e < 4; ++e) {
            const int row = r0 + ah * 4 + e;
            feat[(size_t)row * NF + col] = f2bf(acc[nt][e]);
        }
    }

    // epilogue 2: fused el/er (wave holds full rows). head h = cols [h*64, h*64+64)
    float Al[12], Ar[12];
    #pragma unroll
    for (int nt = 0; nt < 12; ++nt) {
        Al[nt] = attn_l[nt * 16 + al];
        Ar[nt] = attn_r[nt * 16 + al];
    }
    #pragma unroll
    for (int h = 0; h < 3; ++h) {
        #pragma unroll
        for (int e = 0; e < 4; ++e) {
            float sl = 0.f, sr = 0.f;
            #pragma unroll
            for (int q = 0; q < 4; ++q) {
                const int nt = h * 4 + q;
                sl += acc[nt][e] * Al[nt];
                sr += acc[nt][e] * Ar[nt];
            }
            #pragma unroll
            for (int m = 1; m <= 8; m <<= 1) {
                sl += __shfl_xor(sl, m);
                sr += __shfl_xor(sr, m);
            }
            if (al == 0) {
                const int row = r0 + ah * 4 + e;
                el[row * 3 + h] = sl;
                if (row < N_DSTN) er[row * 3 + h] = sr;
            }
        }
    }
}

// ---------------- gather: edge softmax (no max shift) + weighted accumulate --
__launch_bounds__(256)
__global__ void gather_kernel(const unsigned short* __restrict__ feat,
                              const float* __restrict__ el, const float* __restrict__ er,
                              const int* __restrict__ src, const int* __restrict__ rp,
                              float* __restrict__ out) {
    const int lane = threadIdx.x & 63;
    const int d = (blockIdx.x * blockDim.x + threadIdx.x) >> 6;
    if (d >= N_DSTN) return;
    const int lo = rp[d], hi = rp[d + 1];
    const float er0 = er[d * 3 + 0], er1 = er[d * 3 + 1], er2 = er[d * 3 + 2];

    float a0 = 0.f, a1 = 0.f, a2 = 0.f, s0 = 0.f, s1 = 0.f, s2 = 0.f;
    for (int base = lo; base < hi; base += 64) {
        const int cnt = min(64, hi - base);
        int sv = 0; float w0 = 0.f, w1 = 0.f, w2 = 0.f;
        if (lane < cnt) {
            sv = src[base + lane];
            float e0 = el[sv * 3 + 0] + er0; e0 = e0 >= 0.f ? e0 : SLOPE * e0; w0 = __expf(e0);
            float e1 = el[sv * 3 + 1] + er1; e1 = e1 >= 0.f ? e1 : SLOPE * e1; w1 = __expf(e1);
            float e2 = el[sv * 3 + 2] + er2; e2 = e2 >= 0.f ? e2 : SLOPE * e2; w2 = __expf(e2);
        }
        int j = 0;
        for (; j + 8 <= cnt; j += 8) {
            unsigned short f0[8], f1[8], f2[8];
            float u0[8], u1[8], u2[8];
            #pragma unroll
            for (int q = 0; q < 8; ++q) {
                const int sj = __shfl(sv, j + q);
                const unsigned short* fp = &feat[(size_t)sj * NF + lane];
                f0[q] = fp[0]; f1[q] = fp[64]; f2[q] = fp[128];
                u0[q] = __shfl(w0, j + q);
                u1[q] = __shfl(w1, j + q);
                u2[q] = __shfl(w2, j + q);
            }
            #pragma unroll
            for (int q = 0; q < 8; ++q) {
                s0 += u0[q]; a0 += u0[q] * bf2f(f0[q]);
                s1 += u1[q]; a1 += u1[q] * bf2f(f1[q]);
                s2 += u2[q]; a2 += u2[q] * bf2f(f2[q]);
            }
        }
        for (; j < cnt; ++j) {
            const int sj = __shfl(sv, j);
            const float u0 = __shfl(w0, j);
            const float u1 = __shfl(w1, j);
            const float u2 = __shfl(w2, j);
            const unsigned short* fp = &feat[(size_t)sj * NF + lane];
            s0 += u0; a0 += u0 * bf2f(fp[0]);
            s1 += u1; a1 += u1 * bf2f(fp[64]);
            s2 += u2; a2 += u2 * bf2f(fp[128]);
        }
    }
    if (hi == lo) { s0 = 1.f; s1 = 1.f; s2 = 1.f; }
    float* op = &out[(size_t)d * NF];
    op[lane]       = a0 / s0;
    op[64 + lane]  = a1 / s1;
    op[128 + lane] = a2 / s2;
}

extern "C" void kernel_launch(void* const* d_in, const int* in_sizes, int n_in,
                              void* d_out, int out_size, void* d_ws, size_t ws_size,
                              hipStream_t stream) {
    const float* x      = (const float*)d_in[0];
    const float* W      = (const float*)d_in[1];
    const float* attn_l = (const float*)d_in[2];
    const float* attn_r = (const float*)d_in[3];
    const int*   src    = (const int*)d_in[4];
    const int*   dst    = (const int*)d_in[5];
    float* out = (float*)d_out;

    char* ws = (char*)d_ws;
    unsigned short* feat = (unsigned short*)ws;             // 76,800,000 B
    float* el = (float*)(ws + 76800000);                    //  2,400,000 B
    float* er = (float*)(ws + 79200000);                    //    600,000 B
    unsigned short* Wp = (unsigned short*)(ws + 79800000);  //     98,304 B
    int*   rp = (int*)(ws + 79898304);                      //    200,004 B

    prep_kernel<<<24 + 196, 256, 0, stream>>>(W, Wp, dst, rp);
    gemm_feat<<<12500, 64, 0, stream>>>(x, Wp, attn_l, attn_r, feat, el, er);
    gather_kernel<<<12500, 256, 0, stream>>>(feat, el, er, src, rp, out);
}